// Round 6
// baseline (211.193 us; speedup 1.0000x reference)
//
#include <hip/hip_runtime.h>

constexpr int N_NODES = 100000;
constexpr int N_EDGES = 1000000;
constexpr int DIM = 64;

constexpr int CAP = 64;     // bucket capacity per node (deg ~ Poisson(10), P(>64)~1e-30)
constexpr int TILE = 64;    // nodes per fused block
constexpr int PAD = 65;     // LDS row stride (floats) — conflict-free
constexpr int BLK = 256;    // 4 waves (512 regressed in R4)

// --- Phase 1: count + scatter, 4 edges/thread = 4 independent atomic chains -
// Pure 4x unroll of the R4-verified per-edge body (scalar loads; compiler
// merges them into dwordx4). Attacks the 75us atomic round-trip serialization.
__global__ __launch_bounds__(256) void count_scatter(
    const int* __restrict__ eidx, int* __restrict__ deg, int* __restrict__ bucket)
{
    int t = blockIdx.x * 256 + threadIdx.x;
    if (t >= N_EDGES / 4) return;
    int e = t * 4;
    int i0 = eidx[e + 0];
    int i1 = eidx[e + 1];
    int i2 = eidx[e + 2];
    int i3 = eidx[e + 3];
    int j0 = eidx[N_EDGES + e + 0];
    int j1 = eidx[N_EDGES + e + 1];
    int j2 = eidx[N_EDGES + e + 2];
    int j3 = eidx[N_EDGES + e + 3];
    // 4 independent round-trips in flight per thread
    int t0 = atomicAdd(&deg[i0], 1);
    int t1 = atomicAdd(&deg[i1], 1);
    int t2 = atomicAdd(&deg[i2], 1);
    int t3 = atomicAdd(&deg[i3], 1);
    if (t0 < CAP) bucket[(size_t)i0 * CAP + t0] = j0;
    if (t1 < CAP) bucket[(size_t)i1 * CAP + t1] = j1;
    if (t2 < CAP) bucket[(size_t)i2 * CAP + t2] = j2;
    if (t3 < CAP) bucket[(size_t)i3 * CAP + t3] = j3;
}

// --- Phase 2 (fused): per-node mean of x rows + 64x64 matmul + bias ---------
// Block = 256 threads = 4 waves, one 64-node tile; each wave does 16 nodes.
// Gather (R3-verified structure): all 64 lanes cooperate per node (lane =
// feature k) -> each edge is one fully-coalesced 256B row read. Bucket
// indices are wave-uniform scalar loads. 8-deep unroll = 2KB in flight/wave.
__global__ __launch_bounds__(BLK) void fused_gather_mm(
    const float* __restrict__ x, const int* __restrict__ deg,
    const int* __restrict__ bucket,
    const float* __restrict__ W, const float* __restrict__ b,
    float* __restrict__ out)
{
    __shared__ float tile[TILE * PAD];   // 16.6 KB

    const int base = blockIdx.x * TILE;
    const int lane = threadIdx.x & 63;
    const int wid  = threadIdx.x >> 6;   // 0..3

    // ---- gather: 16 nodes per wave ----
    for (int i = 0; i < 16; ++i) {
        int row = wid * 16 + i;
        int node = base + row;
        float sum = 0.0f;
        if (node < N_NODES) {
            const int* bk = bucket + (size_t)node * CAP;
            int d = __builtin_amdgcn_readfirstlane(deg[node]);
            if (d > CAP) d = CAP;
            int e = 0;
            for (; e + 8 <= d; e += 8) {
                int j0 = bk[e + 0];
                int j1 = bk[e + 1];
                int j2 = bk[e + 2];
                int j3 = bk[e + 3];
                int j4 = bk[e + 4];
                int j5 = bk[e + 5];
                int j6 = bk[e + 6];
                int j7 = bk[e + 7];
                float v0 = x[(size_t)j0 * DIM + lane];
                float v1 = x[(size_t)j1 * DIM + lane];
                float v2 = x[(size_t)j2 * DIM + lane];
                float v3 = x[(size_t)j3 * DIM + lane];
                float v4 = x[(size_t)j4 * DIM + lane];
                float v5 = x[(size_t)j5 * DIM + lane];
                float v6 = x[(size_t)j6 * DIM + lane];
                float v7 = x[(size_t)j7 * DIM + lane];
                sum += ((v0 + v1) + (v2 + v3)) + ((v4 + v5) + (v6 + v7));
            }
            for (; e + 4 <= d; e += 4) {
                int j0 = bk[e + 0];
                int j1 = bk[e + 1];
                int j2 = bk[e + 2];
                int j3 = bk[e + 3];
                float v0 = x[(size_t)j0 * DIM + lane];
                float v1 = x[(size_t)j1 * DIM + lane];
                float v2 = x[(size_t)j2 * DIM + lane];
                float v3 = x[(size_t)j3 * DIM + lane];
                sum += (v0 + v1) + (v2 + v3);
            }
            for (; e < d; ++e) {
                int j = bk[e];
                sum += x[(size_t)j * DIM + lane];
            }
            float inv = (d > 0) ? 1.0f / (float)d : 0.0f;
            sum *= inv;
        }
        tile[row * PAD + lane] = sum;    // row*65 + lane: conflict-free
    }
    __syncthreads();

    // ---- matmul: thread owns node nd, 16 output dims d0..d0+15 ----
    const int nd  = threadIdx.x & 63;
    const int d0u = __builtin_amdgcn_readfirstlane((threadIdx.x >> 6) << 4);
    const float* __restrict__ Wr = W + (size_t)d0u * DIM;   // uniform -> s_load

    float acc[16];
#pragma unroll
    for (int q = 0; q < 16; ++q) acc[q] = 0.0f;

#pragma unroll 4
    for (int k = 0; k < DIM; ++k) {
        float a = tile[nd * PAD + k];    // lane*65+k: conflict-free
#pragma unroll
        for (int q = 0; q < 16; ++q)
            acc[q] = fmaf(a, Wr[(size_t)q * DIM + k], acc[q]);
    }

    // ---- epilogue: mask + bias, LDS round-trip for coalesced store ----
    int gnode = base + nd;
    int dg = (gnode < N_NODES) ? deg[gnode] : 0;
    __syncthreads();                     // everyone done reading agg
#pragma unroll
    for (int q = 0; q < 16; ++q) {
        float v = (dg > 0) ? (acc[q] + b[d0u + q]) : 0.0f;
        tile[nd * PAD + d0u + q] = v;
    }
    __syncthreads();

#pragma unroll
    for (int r = 0; r < 16; ++r) {
        int idx = r * BLK + threadIdx.x;           // 0..4095
        int row = idx >> 6, d = idx & 63;
        int g = base + row;
        if (g < N_NODES)
            out[(size_t)g * DIM + d] = tile[row * PAD + d];
    }
}

extern "C" void kernel_launch(void* const* d_in, const int* in_sizes, int n_in,
                              void* d_out, int out_size, void* d_ws, size_t ws_size,
                              hipStream_t stream) {
    const float* x  = (const float*)d_in[0];   // (N, 64)
    const int*   ei = (const int*)d_in[1];     // (2, E): [0,E) targets, [E,2E) sources
    const float* W  = (const float*)d_in[2];   // (64, 64)
    const float* b  = (const float*)d_in[3];   // (64,)
    float* out = (float*)d_out;                // (N, 64)

    int* deg    = (int*)d_ws;                  // N
    int* bucket = deg + N_NODES;               // N * CAP (25.6 MB)

    hipMemsetAsync(deg, 0, N_NODES * sizeof(int), stream);
    count_scatter<<<(N_EDGES / 4 + 255) / 256, 256, 0, stream>>>(ei, deg, bucket);
    fused_gather_mm<<<(N_NODES + TILE - 1) / TILE, BLK, 0, stream>>>(
        x, deg, bucket, W, b, out);
}